// Round 1
// baseline (3313.174 us; speedup 1.0000x reference)
//
#include <hip/hip_runtime.h>

// Cross-attention forward: B=2, N1=N2=2048, HID=768, 12 heads x 64.
// Outputs: ctx [B,N1,768] fp32, attn_weights [B,N1,N2] fp32 (concat in d_out).
// Round 1: pure fp32 (accuracy threshold 1.4e-3 rules out naive bf16 MFMA).

constexpr int B_  = 2;
constexpr int N_  = 2048;   // N1 == N2
constexpr int HID = 768;
constexpr int NH  = 12;
constexpr int HD  = 64;

// ---------------------------------------------------------------------------
// K1: QKV projection.  grid (M/64, HID/64, 3), block 256.
// which=0: q = s1@Wq + bq  -> qws  [b][h][n][d]
// which=1: k = s2@Wk + bk  -> kTws [b][h][d][n]   (transposed for coalesced QK)
// which=2: v = s2@Wv + bv  -> vws  [b][h][n][d]
// ---------------------------------------------------------------------------
__global__ __launch_bounds__(256) void proj_kernel(
    const float* __restrict__ s1, const float* __restrict__ s2,
    const float* __restrict__ Wq, const float* __restrict__ bq,
    const float* __restrict__ Wk, const float* __restrict__ bk,
    const float* __restrict__ Wv, const float* __restrict__ bv,
    float* __restrict__ qws, float* __restrict__ kTws, float* __restrict__ vws)
{
    const int which = blockIdx.z;
    const float* __restrict__ X    = (which == 0) ? s1 : s2;
    const float* __restrict__ W    = (which == 0) ? Wq : (which == 1) ? Wk : Wv;
    const float* __restrict__ bias = (which == 0) ? bq : (which == 1) ? bk : bv;

    const int row0 = blockIdx.x * 64;
    const int col0 = blockIdx.y * 64;
    const int t  = threadIdx.x;
    const int tx = t % 16;      // col group (4 cols each)
    const int ty = t / 16;      // row group (4 rows each)

    __shared__ float As[16][65];   // [kk][row]
    __shared__ float Bs[16][68];   // [kk][col], 16B-aligned rows

    // loader indices
    const int lr = t / 4;            // 0..63 row
    const int lk = (t % 4) * 4;      // 0,4,8,12
    const int bk_row = t / 16;       // 0..15 kk
    const int bc = (t % 16) * 4;     // 0..60 col

    float acc[4][4] = {};

    for (int k0 = 0; k0 < HID; k0 += 16) {
        float4 av  = *reinterpret_cast<const float4*>(&X[(size_t)(row0 + lr) * HID + k0 + lk]);
        float4 bv4 = *reinterpret_cast<const float4*>(&W[(size_t)(k0 + bk_row) * HID + col0 + bc]);
        As[lk + 0][lr] = av.x;
        As[lk + 1][lr] = av.y;
        As[lk + 2][lr] = av.z;
        As[lk + 3][lr] = av.w;
        *reinterpret_cast<float4*>(&Bs[bk_row][bc]) = bv4;
        __syncthreads();

        #pragma unroll
        for (int kk = 0; kk < 16; ++kk) {
            float a[4], bb[4];
            #pragma unroll
            for (int i = 0; i < 4; ++i) a[i]  = As[kk][ty * 4 + i];
            #pragma unroll
            for (int j = 0; j < 4; ++j) bb[j] = Bs[kk][tx * 4 + j];
            #pragma unroll
            for (int i = 0; i < 4; ++i)
                #pragma unroll
                for (int j = 0; j < 4; ++j)
                    acc[i][j] = fmaf(a[i], bb[j], acc[i][j]);
        }
        __syncthreads();
    }

    const int b = row0 / N_;   // 64 | 2048, so whole tile is one batch
    #pragma unroll
    for (int i = 0; i < 4; ++i) {
        const int row = row0 + ty * 4 + i;
        const int n   = row % N_;
        #pragma unroll
        for (int j = 0; j < 4; ++j) {
            const int col  = col0 + tx * 4 + j;
            const int head = col / HD;
            const int dd   = col % HD;
            const float val = acc[i][j] + bias[col];
            if (which == 0)
                qws[(((size_t)(b * NH + head)) * N_ + n) * HD + dd] = val;
            else if (which == 1)
                kTws[(((size_t)(b * NH + head)) * HD + dd) * N_ + n] = val;
            else
                vws[(((size_t)(b * NH + head)) * N_ + n) * HD + dd] = val;
        }
    }
}

// ---------------------------------------------------------------------------
// K2: flash attention per (b,h,32-row q tile). Online softmax; writes
// ctx (normalized) + per-row m,l stats for K3.  grid (N/32, NH, B), block 256.
// Wave w owns rows w*8..w*8+7; lane = k-column (QK) / d-column (PV).
// ---------------------------------------------------------------------------
__global__ __launch_bounds__(256) void flash_kernel(
    const float* __restrict__ qws, const float* __restrict__ kTws,
    const float* __restrict__ vws, const float* __restrict__ mask,
    float* __restrict__ out_ctx, float* __restrict__ m_ws, float* __restrict__ l_ws)
{
    const int qt = blockIdx.x, h = blockIdx.y, b = blockIdx.z;
    const int lane = threadIdx.x & 63;
    const int wave = threadIdx.x >> 6;

    __shared__ float q_s[32][HD];     // broadcast reads, no pad needed
    __shared__ float p_s[32][68];     // pad 68: float4-aligned rows, conflict-free writes

    const float* __restrict__ qptr = qws  + (((size_t)(b * NH + h)) * N_ + (size_t)qt * 32) * HD;
    const float* __restrict__ kT   = kTws + ((size_t)(b * NH + h)) * HD * N_;
    const float* __restrict__ vp   = vws  + ((size_t)(b * NH + h)) * N_ * HD;
    const float* __restrict__ mk   = mask + (size_t)b * N_;

    // load q tile, pre-scaled by 1/sqrt(d)
    for (int e = threadIdx.x; e < 32 * HD; e += 256)
        q_s[e / HD][e % HD] = qptr[e] * 0.125f;
    __syncthreads();

    float mrow[8], lrow[8], cacc[8];
    #pragma unroll
    for (int j = 0; j < 8; ++j) { mrow[j] = -1e30f; lrow[j] = 0.f; cacc[j] = 0.f; }

    for (int k0 = 0; k0 < N_; k0 += 64) {
        // ---- scores: s[j] = q_row_j . k_(k0+lane) ----
        float s[8];
        #pragma unroll
        for (int j = 0; j < 8; ++j) s[j] = 0.f;
        const float* kcol = kT + k0 + lane;
        #pragma unroll
        for (int d0 = 0; d0 < HD; d0 += 4) {
            const float kv0 = kcol[(size_t)(d0 + 0) * N_];
            const float kv1 = kcol[(size_t)(d0 + 1) * N_];
            const float kv2 = kcol[(size_t)(d0 + 2) * N_];
            const float kv3 = kcol[(size_t)(d0 + 3) * N_];
            #pragma unroll
            for (int j = 0; j < 8; ++j) {
                const float4 qv = *reinterpret_cast<const float4*>(&q_s[wave * 8 + j][d0]);
                s[j] = fmaf(qv.x, kv0, s[j]);
                s[j] = fmaf(qv.y, kv1, s[j]);
                s[j] = fmaf(qv.z, kv2, s[j]);
                s[j] = fmaf(qv.w, kv3, s[j]);
            }
        }
        const float mv = mk[k0 + lane];
        // ---- online softmax per row (reduce over 64 lanes = 64 k's) ----
        #pragma unroll
        for (int j = 0; j < 8; ++j) {
            float sv = s[j] + mv;
            float rmax = sv;
            #pragma unroll
            for (int off = 32; off; off >>= 1) rmax = fmaxf(rmax, __shfl_xor(rmax, off));
            const float mnew  = fmaxf(mrow[j], rmax);
            const float scale = __expf(mrow[j] - mnew);
            const float p     = __expf(sv - mnew);
            float psum = p;
            #pragma unroll
            for (int off = 32; off; off >>= 1) psum += __shfl_xor(psum, off);
            lrow[j] = lrow[j] * scale + psum;
            cacc[j] *= scale;
            mrow[j] = mnew;
            p_s[wave * 8 + j][lane] = p;
        }
        __syncthreads();   // order p_s writes before reads (conservative)
        // ---- PV: cacc[j] += sum_k p[j][k] * v[k0+k][lane] ----
        const float* vrow = vp + (size_t)k0 * HD + lane;
        #pragma unroll
        for (int k = 0; k < 64; k += 4) {
            const float vv0 = vrow[(size_t)(k + 0) * HD];
            const float vv1 = vrow[(size_t)(k + 1) * HD];
            const float vv2 = vrow[(size_t)(k + 2) * HD];
            const float vv3 = vrow[(size_t)(k + 3) * HD];
            #pragma unroll
            for (int j = 0; j < 8; ++j) {
                const float4 pv = *reinterpret_cast<const float4*>(&p_s[wave * 8 + j][k]);
                cacc[j] = fmaf(pv.x, vv0, cacc[j]);
                cacc[j] = fmaf(pv.y, vv1, cacc[j]);
                cacc[j] = fmaf(pv.z, vv2, cacc[j]);
                cacc[j] = fmaf(pv.w, vv3, cacc[j]);
            }
        }
        __syncthreads();   // p_s reuse next iteration
    }

    #pragma unroll
    for (int j = 0; j < 8; ++j) {
        const int r = qt * 32 + wave * 8 + j;
        const float inv = 1.f / lrow[j];
        out_ctx[((size_t)(b * N_ + r)) * HID + h * HD + lane] = cacc[j] * inv;
        if (lane == 0) {
            m_ws[((size_t)(b * NH + h)) * N_ + r] = mrow[j];
            l_ws[((size_t)(b * NH + h)) * N_ + r] = lrow[j];
        }
    }
}

// ---------------------------------------------------------------------------
// K3: attn_weights = sum_h probs / 12.  grid (N/16, B), block 256.
// Recomputes scores per head with final (m,l): exact softmax, no atomics.
// Thread t: col c = t%128 within k-tile, row group rg = t/128 (8 rows each).
// ---------------------------------------------------------------------------
constexpr int QT3 = 16;
__global__ __launch_bounds__(256) void attnw_kernel(
    const float* __restrict__ qws, const float* __restrict__ kTws,
    const float* __restrict__ mask, const float* __restrict__ m_ws,
    const float* __restrict__ l_ws, float* __restrict__ out_attn)
{
    const int qt = blockIdx.x, b = blockIdx.y;
    const int t = threadIdx.x;

    __shared__ float q_s[NH][QT3][HD];          // 48 KB
    __shared__ float m_s[NH][QT3], li_s[NH][QT3];

    for (int e = t; e < NH * QT3 * HD; e += 256) {
        const int hh = e / (QT3 * HD);
        const int rr = (e / HD) % QT3;
        const int dd = e % HD;
        q_s[hh][rr][dd] = qws[(((size_t)(b * NH + hh)) * N_ + (size_t)qt * QT3 + rr) * HD + dd] * 0.125f;
    }
    if (t < NH * QT3) {
        const int hh = t / QT3, rr = t % QT3;
        m_s[hh][rr]  = m_ws[((size_t)(b * NH + hh)) * N_ + qt * QT3 + rr];
        li_s[hh][rr] = 1.f / l_ws[((size_t)(b * NH + hh)) * N_ + qt * QT3 + rr];
    }
    __syncthreads();

    const int c  = t % 128;
    const int rg = t / 128;    // 0..1 -> rows rg*8..rg*8+7

    for (int k0 = 0; k0 < N_; k0 += 128) {
        float accw[8] = {};
        const float mv = mask[(size_t)b * N_ + k0 + c];
        for (int hh = 0; hh < NH; ++hh) {
            const float* kcol = kTws + ((size_t)(b * NH + hh)) * HD * N_ + k0 + c;
            float s[8] = {};
            #pragma unroll
            for (int d0 = 0; d0 < HD; d0 += 4) {
                const float kv0 = kcol[(size_t)(d0 + 0) * N_];
                const float kv1 = kcol[(size_t)(d0 + 1) * N_];
                const float kv2 = kcol[(size_t)(d0 + 2) * N_];
                const float kv3 = kcol[(size_t)(d0 + 3) * N_];
                #pragma unroll
                for (int j = 0; j < 8; ++j) {
                    const float4 qv = *reinterpret_cast<const float4*>(&q_s[hh][rg * 8 + j][d0]);
                    s[j] = fmaf(qv.x, kv0, s[j]);
                    s[j] = fmaf(qv.y, kv1, s[j]);
                    s[j] = fmaf(qv.z, kv2, s[j]);
                    s[j] = fmaf(qv.w, kv3, s[j]);
                }
            }
            #pragma unroll
            for (int j = 0; j < 8; ++j)
                accw[j] += __expf(s[j] + mv - m_s[hh][rg * 8 + j]) * li_s[hh][rg * 8 + j];
        }
        #pragma unroll
        for (int j = 0; j < 8; ++j)
            out_attn[((size_t)(b * N_ + (size_t)qt * QT3 + rg * 8 + j)) * N_ + k0 + c]
                = accw[j] * (1.0f / 12.0f);
    }
}

// ---------------------------------------------------------------------------
extern "C" void kernel_launch(void* const* d_in, const int* in_sizes, int n_in,
                              void* d_out, int out_size, void* d_ws, size_t ws_size,
                              hipStream_t stream) {
    (void)in_sizes; (void)n_in; (void)out_size; (void)ws_size;
    const float* s1   = (const float*)d_in[0];
    const float* s2   = (const float*)d_in[1];
    const float* mask = (const float*)d_in[2];
    const float* Wq   = (const float*)d_in[3];
    const float* bq   = (const float*)d_in[4];
    const float* Wk   = (const float*)d_in[5];
    const float* bk   = (const float*)d_in[6];
    const float* Wv   = (const float*)d_in[7];
    const float* bv   = (const float*)d_in[8];

    float* out_ctx  = (float*)d_out;
    float* out_attn = out_ctx + (size_t)B_ * N_ * HID;

    float* ws   = (float*)d_ws;
    const size_t qkv_elems = (size_t)B_ * NH * N_ * HD;   // 3,145,728
    float* qws  = ws;
    float* kTws = qws  + qkv_elems;
    float* vws  = kTws + qkv_elems;
    float* m_ws = vws  + qkv_elems;
    float* l_ws = m_ws + (size_t)B_ * NH * N_;

    dim3 g1((B_ * N_) / 64, HID / 64, 3);
    proj_kernel<<<g1, 256, 0, stream>>>(s1, s2, Wq, bq, Wk, bk, Wv, bv, qws, kTws, vws);

    dim3 g2(N_ / 32, NH, B_);
    flash_kernel<<<g2, 256, 0, stream>>>(qws, kTws, vws, mask, out_ctx, m_ws, l_ws);

    dim3 g3(N_ / QT3, B_);
    attnw_kernel<<<g3, 256, 0, stream>>>(qws, kTws, mask, m_ws, l_ws, out_attn);
}

// Round 2
// 1055.131 us; speedup vs baseline: 3.1401x; 3.1401x over previous
//
#include <hip/hip_runtime.h>

// Cross-attention forward: B=2, N1=N2=2048, HID=768, 12 heads x 64.
// Outputs: ctx [B,N1,768] fp32, attn_weights [B,N1,N2] fp32 (concat in d_out).
// Round 2: q/m/l read as wave-uniform scalar loads (s_load) instead of LDS;
// attnw re-gridded 256 -> 2048 blocks, no LDS; flash k-tile 256, no barriers.

constexpr int B_  = 2;
constexpr int N_  = 2048;   // N1 == N2
constexpr int HID = 768;
constexpr int NH  = 12;
constexpr int HD  = 64;

// ---------------------------------------------------------------------------
// K1: QKV projection.  grid (M/64, HID/64, 3), block 256.
// which=0: q = s1@Wq + bq  -> qws  [b][h][n][d]
// which=1: k = s2@Wk + bk  -> kTws [b][h][d][n]   (transposed for coalesced QK)
// which=2: v = s2@Wv + bv  -> vws  [b][h][n][d]
// ---------------------------------------------------------------------------
__global__ __launch_bounds__(256) void proj_kernel(
    const float* __restrict__ s1, const float* __restrict__ s2,
    const float* __restrict__ Wq, const float* __restrict__ bq,
    const float* __restrict__ Wk, const float* __restrict__ bk,
    const float* __restrict__ Wv, const float* __restrict__ bv,
    float* __restrict__ qws, float* __restrict__ kTws, float* __restrict__ vws)
{
    const int which = blockIdx.z;
    const float* __restrict__ X    = (which == 0) ? s1 : s2;
    const float* __restrict__ W    = (which == 0) ? Wq : (which == 1) ? Wk : Wv;
    const float* __restrict__ bias = (which == 0) ? bq : (which == 1) ? bk : bv;

    const int row0 = blockIdx.x * 64;
    const int col0 = blockIdx.y * 64;
    const int t  = threadIdx.x;
    const int tx = t % 16;      // col group (4 cols each)
    const int ty = t / 16;      // row group (4 rows each)

    __shared__ float As[16][65];   // [kk][row]
    __shared__ float Bs[16][68];   // [kk][col]

    const int lr = t / 4;            // 0..63 row
    const int lk = (t % 4) * 4;      // 0,4,8,12
    const int bk_row = t / 16;       // 0..15 kk
    const int bc = (t % 16) * 4;     // 0..60 col

    float acc[4][4] = {};

    for (int k0 = 0; k0 < HID; k0 += 16) {
        float4 av  = *reinterpret_cast<const float4*>(&X[(size_t)(row0 + lr) * HID + k0 + lk]);
        float4 bv4 = *reinterpret_cast<const float4*>(&W[(size_t)(k0 + bk_row) * HID + col0 + bc]);
        As[lk + 0][lr] = av.x;
        As[lk + 1][lr] = av.y;
        As[lk + 2][lr] = av.z;
        As[lk + 3][lr] = av.w;
        *reinterpret_cast<float4*>(&Bs[bk_row][bc]) = bv4;
        __syncthreads();

        #pragma unroll
        for (int kk = 0; kk < 16; ++kk) {
            float a[4], bb[4];
            #pragma unroll
            for (int i = 0; i < 4; ++i) a[i]  = As[kk][ty * 4 + i];
            #pragma unroll
            for (int j = 0; j < 4; ++j) bb[j] = Bs[kk][tx * 4 + j];
            #pragma unroll
            for (int i = 0; i < 4; ++i)
                #pragma unroll
                for (int j = 0; j < 4; ++j)
                    acc[i][j] = fmaf(a[i], bb[j], acc[i][j]);
        }
        __syncthreads();
    }

    const int b = row0 / N_;   // 64 | 2048, so whole tile is one batch
    #pragma unroll
    for (int i = 0; i < 4; ++i) {
        const int row = row0 + ty * 4 + i;
        const int n   = row % N_;
        #pragma unroll
        for (int j = 0; j < 4; ++j) {
            const int col  = col0 + tx * 4 + j;
            const int head = col / HD;
            const int dd   = col % HD;
            const float val = acc[i][j] + bias[col];
            if (which == 0)
                qws[(((size_t)(b * NH + head)) * N_ + n) * HD + dd] = val;
            else if (which == 1)
                kTws[(((size_t)(b * NH + head)) * HD + dd) * N_ + n] = val;
            else
                vws[(((size_t)(b * NH + head)) * N_ + n) * HD + dd] = val;
        }
    }
}

// ---------------------------------------------------------------------------
// K2: flash attention per (b,h,32-row q tile). grid (N/32, NH, B), block 256.
// Wave w owns rows w*8..w*8+7 (wave-private -> NO barriers in the k-loop).
// k-tile = 256: lane owns 4 k-cols. q is read via wave-uniform global loads
// (scalar pipe); p_s is wave-private LDS used only for the PV broadcast.
// ---------------------------------------------------------------------------
__global__ __launch_bounds__(256) void flash_kernel(
    const float* __restrict__ qws, const float* __restrict__ kTws,
    const float* __restrict__ vws, const float* __restrict__ mask,
    float* __restrict__ out_ctx, float* __restrict__ m_ws, float* __restrict__ l_ws)
{
    const int qt = blockIdx.x, h = blockIdx.y, b = blockIdx.z;
    const int lane = threadIdx.x & 63;
    // force wave index into an SGPR so q addresses are provably uniform
    const int wave = __builtin_amdgcn_readfirstlane(threadIdx.x >> 6);

    __shared__ float p_s[32][256];   // wave-private rows; broadcast reads in PV

    const float* __restrict__ qp = qws + (((size_t)(b * NH + h)) * N_ + (size_t)qt * 32 + wave * 8) * HD;
    const float* __restrict__ kT = kTws + ((size_t)(b * NH + h)) * HD * N_;
    const float* __restrict__ vp = vws  + ((size_t)(b * NH + h)) * N_ * HD;
    const float* __restrict__ mk = mask + (size_t)b * N_;

    float mrow[8], lrow[8], cacc[8];
    #pragma unroll
    for (int j = 0; j < 8; ++j) { mrow[j] = -1e30f; lrow[j] = 0.f; cacc[j] = 0.f; }

    for (int k0 = 0; k0 < N_; k0 += 256) {
        // ---- scores: s[j][cc] = q_row_j . k_(k0+lane*4+cc) ----
        float s[8][4] = {};
        const float* kcol = kT + k0 + lane * 4;
        #pragma unroll 4
        for (int d0 = 0; d0 < HD; d0 += 4) {
            const float4 kv0 = *reinterpret_cast<const float4*>(&kcol[(size_t)(d0 + 0) * N_]);
            const float4 kv1 = *reinterpret_cast<const float4*>(&kcol[(size_t)(d0 + 1) * N_]);
            const float4 kv2 = *reinterpret_cast<const float4*>(&kcol[(size_t)(d0 + 2) * N_]);
            const float4 kv3 = *reinterpret_cast<const float4*>(&kcol[(size_t)(d0 + 3) * N_]);
            #pragma unroll
            for (int j = 0; j < 8; ++j) {
                const float4 qv = *reinterpret_cast<const float4*>(&qp[j * HD + d0]); // uniform -> s_load
                s[j][0] = fmaf(qv.x, kv0.x, s[j][0]);
                s[j][1] = fmaf(qv.x, kv0.y, s[j][1]);
                s[j][2] = fmaf(qv.x, kv0.z, s[j][2]);
                s[j][3] = fmaf(qv.x, kv0.w, s[j][3]);
                s[j][0] = fmaf(qv.y, kv1.x, s[j][0]);
                s[j][1] = fmaf(qv.y, kv1.y, s[j][1]);
                s[j][2] = fmaf(qv.y, kv1.z, s[j][2]);
                s[j][3] = fmaf(qv.y, kv1.w, s[j][3]);
                s[j][0] = fmaf(qv.z, kv2.x, s[j][0]);
                s[j][1] = fmaf(qv.z, kv2.y, s[j][1]);
                s[j][2] = fmaf(qv.z, kv2.z, s[j][2]);
                s[j][3] = fmaf(qv.z, kv2.w, s[j][3]);
                s[j][0] = fmaf(qv.w, kv3.x, s[j][0]);
                s[j][1] = fmaf(qv.w, kv3.y, s[j][1]);
                s[j][2] = fmaf(qv.w, kv3.z, s[j][2]);
                s[j][3] = fmaf(qv.w, kv3.w, s[j][3]);
            }
        }
        const float4 mv = *reinterpret_cast<const float4*>(&mk[k0 + lane * 4]);
        // ---- online softmax per row (256 cols = 4/lane x 64 lanes) ----
        #pragma unroll
        for (int j = 0; j < 8; ++j) {
            float sc0 = s[j][0] * 0.125f + mv.x;
            float sc1 = s[j][1] * 0.125f + mv.y;
            float sc2 = s[j][2] * 0.125f + mv.z;
            float sc3 = s[j][3] * 0.125f + mv.w;
            float rmax = fmaxf(fmaxf(sc0, sc1), fmaxf(sc2, sc3));
            #pragma unroll
            for (int off = 32; off; off >>= 1) rmax = fmaxf(rmax, __shfl_xor(rmax, off));
            const float mnew  = fmaxf(mrow[j], rmax);
            const float scale = __expf(mrow[j] - mnew);
            const float p0 = __expf(sc0 - mnew);
            const float p1 = __expf(sc1 - mnew);
            const float p2 = __expf(sc2 - mnew);
            const float p3 = __expf(sc3 - mnew);
            float psum = (p0 + p1) + (p2 + p3);
            #pragma unroll
            for (int off = 32; off; off >>= 1) psum += __shfl_xor(psum, off);
            lrow[j] = lrow[j] * scale + psum;
            cacc[j] *= scale;
            mrow[j] = mnew;
            *reinterpret_cast<float4*>(&p_s[wave * 8 + j][lane * 4]) = make_float4(p0, p1, p2, p3);
        }
        // ---- PV: cacc[j] += sum_k p[j][k] * v[k0+k][lane] ----
        // p_s rows are wave-private: in-wave lgkmcnt ordering suffices, no barrier.
        const float* vrow = vp + (size_t)k0 * HD + lane;
        #pragma unroll 4
        for (int k = 0; k < 256; k += 4) {
            const float vv0 = vrow[(size_t)(k + 0) * HD];
            const float vv1 = vrow[(size_t)(k + 1) * HD];
            const float vv2 = vrow[(size_t)(k + 2) * HD];
            const float vv3 = vrow[(size_t)(k + 3) * HD];
            #pragma unroll
            for (int j = 0; j < 8; ++j) {
                const float4 pv = *reinterpret_cast<const float4*>(&p_s[wave * 8 + j][k]);
                cacc[j] = fmaf(pv.x, vv0, cacc[j]);
                cacc[j] = fmaf(pv.y, vv1, cacc[j]);
                cacc[j] = fmaf(pv.z, vv2, cacc[j]);
                cacc[j] = fmaf(pv.w, vv3, cacc[j]);
            }
        }
    }

    #pragma unroll
    for (int j = 0; j < 8; ++j) {
        const int r = qt * 32 + wave * 8 + j;
        const float inv = 1.f / lrow[j];
        out_ctx[((size_t)(b * N_ + r)) * HID + h * HD + lane] = cacc[j] * inv;
        if (lane == 0) {
            m_ws[((size_t)(b * NH + h)) * N_ + r] = mrow[j];
            l_ws[((size_t)(b * NH + h)) * N_ + r] = lrow[j];
        }
    }
}

// ---------------------------------------------------------------------------
// K3: attn_weights = sum_h probs / 12.  grid (N1/8, N2/512, B), block 256.
// No LDS. Each thread: 2 cols x 8 rows. q/m/l via wave-uniform scalar loads.
// ---------------------------------------------------------------------------
__global__ __launch_bounds__(256) void attnw_kernel(
    const float* __restrict__ qws, const float* __restrict__ kTws,
    const float* __restrict__ mask, const float* __restrict__ m_ws,
    const float* __restrict__ l_ws, float* __restrict__ out_attn)
{
    const int qt = blockIdx.x;           // row tile of 8
    const int ct = blockIdx.y;           // col tile of 512
    const int b  = blockIdx.z;
    const int t  = threadIdx.x;
    const int c0 = ct * 512 + t * 2;     // 2 cols per thread
    const int r0 = qt * 8;

    float accw[8][2] = {};
    const float2 mv = *reinterpret_cast<const float2*>(&mask[(size_t)b * N_ + c0]);

    for (int hh = 0; hh < NH; ++hh) {
        const float* __restrict__ qp   = qws  + (((size_t)(b * NH + hh)) * N_ + r0) * HD;
        const float* __restrict__ kcol = kTws + ((size_t)(b * NH + hh)) * HD * N_ + c0;
        const float* __restrict__ mrow = m_ws + ((size_t)(b * NH + hh)) * N_ + r0;
        const float* __restrict__ lrow = l_ws + ((size_t)(b * NH + hh)) * N_ + r0;

        float s[8][2] = {};
        #pragma unroll 4
        for (int d0 = 0; d0 < HD; d0 += 4) {
            const float2 kv0 = *reinterpret_cast<const float2*>(&kcol[(size_t)(d0 + 0) * N_]);
            const float2 kv1 = *reinterpret_cast<const float2*>(&kcol[(size_t)(d0 + 1) * N_]);
            const float2 kv2 = *reinterpret_cast<const float2*>(&kcol[(size_t)(d0 + 2) * N_]);
            const float2 kv3 = *reinterpret_cast<const float2*>(&kcol[(size_t)(d0 + 3) * N_]);
            #pragma unroll
            for (int j = 0; j < 8; ++j) {
                const float4 qv = *reinterpret_cast<const float4*>(&qp[j * HD + d0]); // uniform -> s_load
                s[j][0] = fmaf(qv.x, kv0.x, s[j][0]);
                s[j][1] = fmaf(qv.x, kv0.y, s[j][1]);
                s[j][0] = fmaf(qv.y, kv1.x, s[j][0]);
                s[j][1] = fmaf(qv.y, kv1.y, s[j][1]);
                s[j][0] = fmaf(qv.z, kv2.x, s[j][0]);
                s[j][1] = fmaf(qv.z, kv2.y, s[j][1]);
                s[j][0] = fmaf(qv.w, kv3.x, s[j][0]);
                s[j][1] = fmaf(qv.w, kv3.y, s[j][1]);
            }
        }
        #pragma unroll
        for (int j = 0; j < 8; ++j) {
            const float mj  = mrow[j];          // uniform -> s_load
            const float lij = 1.f / lrow[j];    // uniform -> s_load
            accw[j][0] += __expf(s[j][0] * 0.125f + mv.x - mj) * lij;
            accw[j][1] += __expf(s[j][1] * 0.125f + mv.y - mj) * lij;
        }
    }

    #pragma unroll
    for (int j = 0; j < 8; ++j) {
        const float2 o = make_float2(accw[j][0] * (1.0f / 12.0f), accw[j][1] * (1.0f / 12.0f));
        *reinterpret_cast<float2*>(&out_attn[((size_t)(b * N_ + r0 + j)) * N_ + c0]) = o;
    }
}

// ---------------------------------------------------------------------------
extern "C" void kernel_launch(void* const* d_in, const int* in_sizes, int n_in,
                              void* d_out, int out_size, void* d_ws, size_t ws_size,
                              hipStream_t stream) {
    (void)in_sizes; (void)n_in; (void)out_size; (void)ws_size;
    const float* s1   = (const float*)d_in[0];
    const float* s2   = (const float*)d_in[1];
    const float* mask = (const float*)d_in[2];
    const float* Wq   = (const float*)d_in[3];
    const float* bq   = (const float*)d_in[4];
    const float* Wk   = (const float*)d_in[5];
    const float* bk   = (const float*)d_in[6];
    const float* Wv   = (const float*)d_in[7];
    const float* bv   = (const float*)d_in[8];

    float* out_ctx  = (float*)d_out;
    float* out_attn = out_ctx + (size_t)B_ * N_ * HID;

    float* ws   = (float*)d_ws;
    const size_t qkv_elems = (size_t)B_ * NH * N_ * HD;   // 3,145,728
    float* qws  = ws;
    float* kTws = qws  + qkv_elems;
    float* vws  = kTws + qkv_elems;
    float* m_ws = vws  + qkv_elems;
    float* l_ws = m_ws + (size_t)B_ * NH * N_;

    dim3 g1((B_ * N_) / 64, HID / 64, 3);
    proj_kernel<<<g1, 256, 0, stream>>>(s1, s2, Wq, bq, Wk, bk, Wv, bv, qws, kTws, vws);

    dim3 g2(N_ / 32, NH, B_);
    flash_kernel<<<g2, 256, 0, stream>>>(qws, kTws, vws, mask, out_ctx, m_ws, l_ws);

    dim3 g3(N_ / 8, N_ / 512, B_);
    attnw_kernel<<<g3, 256, 0, stream>>>(qws, kTws, mask, m_ws, l_ws, out_attn);
}

// Round 3
// 599.253 us; speedup vs baseline: 5.5288x; 1.7607x over previous
//
#include <hip/hip_runtime.h>
#include <stdint.h>

// Cross-attention forward: B=2, N1=N2=2048, HID=768, 12 heads x 64.
// Round 3: bf16 MFMA for QK^T and PV (flash) and score recompute (attnw).
// proj stays fp32-compute, now emits bf16 q (pre-scaled by 1/8), k, and V^T.
// flash computes S^T = mfma(K,Q): its C-layout (key=(l>>4)*4+reg, q=l&15) is
// exactly the A-frag layout of mfma_16x16x16bf16_1k, so P stays in registers.

typedef __attribute__((ext_vector_type(8))) short bf16x8;
typedef __attribute__((ext_vector_type(4))) short bf16x4;
typedef __attribute__((ext_vector_type(4))) float f32x4;

constexpr int B_  = 2;
constexpr int N_  = 2048;   // N1 == N2
constexpr int HID = 768;
constexpr int NH  = 12;
constexpr int HD  = 64;

__device__ __forceinline__ short f2bf(float f) {   // RNE float->bf16
    uint32_t u = __builtin_bit_cast(uint32_t, f);
    u = (u + 0x7fffu + ((u >> 16) & 1u)) >> 16;
    return (short)u;
}

// ---------------------------------------------------------------------------
// K1: QKV projection (fp32 GEMM).  grid (M/64, HID/64, 3), block 256.
// which=0: q*0.125 -> qb  [b][h][n][d]  bf16
// which=1: k       -> kbm [b][h][n][d]  bf16
// which=2: v       -> vtb [b][h][d][n]  bf16 (transposed for PV B-frags)
// ---------------------------------------------------------------------------
__global__ __launch_bounds__(256) void proj_kernel(
    const float* __restrict__ s1, const float* __restrict__ s2,
    const float* __restrict__ Wq, const float* __restrict__ bq,
    const float* __restrict__ Wk, const float* __restrict__ bk,
    const float* __restrict__ Wv, const float* __restrict__ bv,
    short* __restrict__ qb, short* __restrict__ kbm, short* __restrict__ vtb)
{
    const int which = blockIdx.z;
    const float* __restrict__ X    = (which == 0) ? s1 : s2;
    const float* __restrict__ W    = (which == 0) ? Wq : (which == 1) ? Wk : Wv;
    const float* __restrict__ bias = (which == 0) ? bq : (which == 1) ? bk : bv;

    const int row0 = blockIdx.x * 64;
    const int col0 = blockIdx.y * 64;
    const int t  = threadIdx.x;
    const int tx = t % 16;
    const int ty = t / 16;

    __shared__ float As[16][65];
    __shared__ float Bs[16][68];

    const int lr = t / 4;
    const int lk = (t % 4) * 4;
    const int bk_row = t / 16;
    const int bc = (t % 16) * 4;

    float acc[4][4] = {};

    for (int k0 = 0; k0 < HID; k0 += 16) {
        float4 av  = *reinterpret_cast<const float4*>(&X[(size_t)(row0 + lr) * HID + k0 + lk]);
        float4 bv4 = *reinterpret_cast<const float4*>(&W[(size_t)(k0 + bk_row) * HID + col0 + bc]);
        As[lk + 0][lr] = av.x;
        As[lk + 1][lr] = av.y;
        As[lk + 2][lr] = av.z;
        As[lk + 3][lr] = av.w;
        *reinterpret_cast<float4*>(&Bs[bk_row][bc]) = bv4;
        __syncthreads();

        #pragma unroll
        for (int kk = 0; kk < 16; ++kk) {
            float a[4], bb[4];
            #pragma unroll
            for (int i = 0; i < 4; ++i) a[i]  = As[kk][ty * 4 + i];
            #pragma unroll
            for (int j = 0; j < 4; ++j) bb[j] = Bs[kk][tx * 4 + j];
            #pragma unroll
            for (int i = 0; i < 4; ++i)
                #pragma unroll
                for (int j = 0; j < 4; ++j)
                    acc[i][j] = fmaf(a[i], bb[j], acc[i][j]);
        }
        __syncthreads();
    }

    const int b    = row0 / N_;       // 64 | 2048 -> tile is in one batch
    const int head = col0 / HD;       // 64-wide tile is in one head
    #pragma unroll
    for (int i = 0; i < 4; ++i) {
        const int n = (row0 + ty * 4 + i) % N_;
        if (which == 2) {
            #pragma unroll
            for (int j = 0; j < 4; ++j) {
                const int dd = tx * 4 + j;
                vtb[((size_t)(b * NH + head) * HD + dd) * N_ + n] = f2bf(acc[i][j] + bias[col0 + dd]);
            }
        } else {
            const float sc = (which == 0) ? 0.125f : 1.0f;   // fold 1/sqrt(64) into q
            short4 pk;
            pk.x = f2bf((acc[i][0] + bias[col0 + tx * 4 + 0]) * sc);
            pk.y = f2bf((acc[i][1] + bias[col0 + tx * 4 + 1]) * sc);
            pk.z = f2bf((acc[i][2] + bias[col0 + tx * 4 + 2]) * sc);
            pk.w = f2bf((acc[i][3] + bias[col0 + tx * 4 + 3]) * sc);
            short* dst = ((which == 0) ? qb : kbm) + ((size_t)(b * NH + head) * N_ + n) * HD + tx * 4;
            *reinterpret_cast<short4*>(dst) = pk;
        }
    }
}

// ---------------------------------------------------------------------------
// K2: flash attention, MFMA.  grid (N/64, NH, B), block 256 (4 waves).
// Wave w owns q rows qt*64+w*16.. +15. No LDS, no barriers.
// Per 64-key tile: S^T = mfma_16x16x32(K,Q) x8; in-register online softmax
// (q is lane-local: 2 shfl_xor rounds); P packed to bf16 feeds
// mfma_16x16x16bf16_1k PV directly (S^T C-layout == PV A-frag layout).
// ---------------------------------------------------------------------------
__global__ __launch_bounds__(256) void flash_kernel(
    const short* __restrict__ qb, const short* __restrict__ kbm,
    const short* __restrict__ vtb, const float* __restrict__ mask,
    float* __restrict__ out_ctx, float* __restrict__ m_ws, float* __restrict__ l_ws)
{
    const int qt = blockIdx.x, h = blockIdx.y, b = blockIdx.z;
    const int lane = threadIdx.x & 63;
    const int wave = threadIdx.x >> 6;
    const int lg = lane >> 4, lm = lane & 15;
    const int q0 = qt * 64 + wave * 16;

    const size_t bh = (size_t)(b * NH + h);
    const short* qp = qb  + (bh * N_ + q0) * HD;
    const short* kp = kbm + bh * N_ * HD;
    const short* vp = vtb + bh * HD * N_;
    const float* mk = mask + (size_t)b * N_;

    // Q B-frag: lane holds Q[q=lm][d=lg*8..+7 (+32)]
    const bf16x8 qf0 = *reinterpret_cast<const bf16x8*>(qp + lm * HD + lg * 8);
    const bf16x8 qf1 = *reinterpret_cast<const bf16x8*>(qp + lm * HD + lg * 8 + 32);

    f32x4 cacc[4];   // ctx acc: cacc[vt][r] -> q = 4*lg+r, d = vt*16+lm
    #pragma unroll
    for (int vt = 0; vt < 4; ++vt) cacc[vt] = f32x4{0.f, 0.f, 0.f, 0.f};
    float m = -1e30f, l = 0.f;

    for (int k0 = 0; k0 < N_; k0 += 64) {
        // S^T tiles: accs[kt][r] = S[key=k0+kt*16+4*lg+r][q=lm] (pre-scaled q)
        f32x4 accs[4];
        #pragma unroll
        for (int kt = 0; kt < 4; ++kt) {
            const short* kr = kp + (size_t)(k0 + kt * 16 + lm) * HD + lg * 8;
            const bf16x8 kf0 = *reinterpret_cast<const bf16x8*>(kr);
            const bf16x8 kf1 = *reinterpret_cast<const bf16x8*>(kr + 32);
            f32x4 z = f32x4{0.f, 0.f, 0.f, 0.f};
            z = __builtin_amdgcn_mfma_f32_16x16x32_bf16(kf0, qf0, z, 0, 0, 0);
            z = __builtin_amdgcn_mfma_f32_16x16x32_bf16(kf1, qf1, z, 0, 0, 0);
            accs[kt] = z;
        }
        // mask + online softmax (per-lane q = lm)
        float p[4][4];
        float tmax = -3.0e38f;
        #pragma unroll
        for (int kt = 0; kt < 4; ++kt) {
            const f32x4 mv = *reinterpret_cast<const f32x4*>(&mk[k0 + kt * 16 + 4 * lg]);
            #pragma unroll
            for (int r = 0; r < 4; ++r) {
                p[kt][r] = accs[kt][r] + mv[r];
                tmax = fmaxf(tmax, p[kt][r]);
            }
        }
        tmax = fmaxf(tmax, __shfl_xor(tmax, 16));
        tmax = fmaxf(tmax, __shfl_xor(tmax, 32));
        const float mnew  = fmaxf(m, tmax);
        const float scale = __expf(m - mnew);
        float psum = 0.f;
        #pragma unroll
        for (int kt = 0; kt < 4; ++kt)
            #pragma unroll
            for (int r = 0; r < 4; ++r) { p[kt][r] = __expf(p[kt][r] - mnew); psum += p[kt][r]; }
        psum += __shfl_xor(psum, 16);
        psum += __shfl_xor(psum, 32);
        l = l * scale + psum;
        m = mnew;
        // pack P -> PV A-frags (reg r == key offset: no data movement)
        bf16x4 pa[4];
        #pragma unroll
        for (int kt = 0; kt < 4; ++kt) {
            bf16x4 t;
            t[0] = f2bf(p[kt][0]); t[1] = f2bf(p[kt][1]);
            t[2] = f2bf(p[kt][2]); t[3] = f2bf(p[kt][3]);
            pa[kt] = t;
        }
        // rescale ctx acc: row q = 4*lg+r needs scale from lane q
        #pragma unroll
        for (int r = 0; r < 4; ++r) {
            const float sr = __shfl(scale, lg * 4 + r);
            #pragma unroll
            for (int vt = 0; vt < 4; ++vt) cacc[vt][r] *= sr;
        }
        // PV: cacc[vt] += P_kt(16x16) * V_kt ; B-frag = 4 contiguous keys of V^T
        #pragma unroll
        for (int kt = 0; kt < 4; ++kt) {
            #pragma unroll
            for (int vt = 0; vt < 4; ++vt) {
                const short* vr = vp + (size_t)(vt * 16 + lm) * N_ + k0 + kt * 16 + lg * 4;
                const bf16x4 vf = *reinterpret_cast<const bf16x4*>(vr);
                cacc[vt] = __builtin_amdgcn_mfma_f32_16x16x16bf16_1k(pa[kt], vf, cacc[vt], 0, 0, 0);
            }
        }
    }

    const float invl = 1.f / l;
    #pragma unroll
    for (int r = 0; r < 4; ++r) {
        const float ir = __shfl(invl, lg * 4 + r);
        float* orow = out_ctx + ((size_t)b * N_ + q0 + lg * 4 + r) * HID + h * HD;
        #pragma unroll
        for (int vt = 0; vt < 4; ++vt) orow[vt * 16 + lm] = cacc[vt][r] * ir;
    }
    if (lane < 16) {
        m_ws[bh * N_ + q0 + lane] = m;
        l_ws[bh * N_ + q0 + lane] = l;
    }
}

// ---------------------------------------------------------------------------
// K3: attn_weights = sum_h probs / 12.  grid (N/16, N/256, B), block 256.
// Wave w: 16 q-rows x 64 keys (kbase = ct*256 + w*64), loops 12 heads.
// S = mfma(Q,K) x8 per head; exact softmax from flash's (m,l). No LDS.
// ---------------------------------------------------------------------------
__global__ __launch_bounds__(256) void attnw_kernel(
    const short* __restrict__ qb, const short* __restrict__ kbm,
    const float* __restrict__ mask, const float* __restrict__ m_ws,
    const float* __restrict__ l_ws, float* __restrict__ out_attn)
{
    const int qt = blockIdx.x, ct = blockIdx.y, b = blockIdx.z;
    const int lane = threadIdx.x & 63;
    const int wave = threadIdx.x >> 6;
    const int lg = lane >> 4, lm = lane & 15;
    const int q0 = qt * 16;
    const int kbase = ct * 256 + wave * 64;

    float mv[4];
    #pragma unroll
    for (int kt = 0; kt < 4; ++kt) mv[kt] = mask[(size_t)b * N_ + kbase + kt * 16 + lm];

    f32x4 accw[4];   // accw[kt][r]: q = 4*lg+r, key = kbase + kt*16 + lm
    #pragma unroll
    for (int kt = 0; kt < 4; ++kt) accw[kt] = f32x4{0.f, 0.f, 0.f, 0.f};

    for (int h = 0; h < NH; ++h) {
        const size_t bh = (size_t)(b * NH + h);
        const short* qp = qb + (bh * N_ + q0) * HD;
        const bf16x8 qf0 = *reinterpret_cast<const bf16x8*>(qp + lm * HD + lg * 8);
        const bf16x8 qf1 = *reinterpret_cast<const bf16x8*>(qp + lm * HD + lg * 8 + 32);
        const short* kp = kbm + bh * N_ * HD;
        float mr[4], il[4];
        #pragma unroll
        for (int r = 0; r < 4; ++r) {
            mr[r] = m_ws[bh * N_ + q0 + lg * 4 + r];
            il[r] = 1.f / l_ws[bh * N_ + q0 + lg * 4 + r];
        }
        #pragma unroll
        for (int kt = 0; kt < 4; ++kt) {
            const short* kr = kp + (size_t)(kbase + kt * 16 + lm) * HD + lg * 8;
            const bf16x8 kf0 = *reinterpret_cast<const bf16x8*>(kr);
            const bf16x8 kf1 = *reinterpret_cast<const bf16x8*>(kr + 32);
            f32x4 z = f32x4{0.f, 0.f, 0.f, 0.f};
            z = __builtin_amdgcn_mfma_f32_16x16x32_bf16(qf0, kf0, z, 0, 0, 0);
            z = __builtin_amdgcn_mfma_f32_16x16x32_bf16(qf1, kf1, z, 0, 0, 0);
            #pragma unroll
            for (int r = 0; r < 4; ++r)
                accw[kt][r] += __expf(z[r] + mv[kt] - mr[r]) * il[r];
        }
    }
    #pragma unroll
    for (int kt = 0; kt < 4; ++kt)
        #pragma unroll
        for (int r = 0; r < 4; ++r)
            out_attn[((size_t)b * N_ + q0 + lg * 4 + r) * N_ + kbase + kt * 16 + lm]
                = accw[kt][r] * (1.0f / 12.0f);
}

// ---------------------------------------------------------------------------
extern "C" void kernel_launch(void* const* d_in, const int* in_sizes, int n_in,
                              void* d_out, int out_size, void* d_ws, size_t ws_size,
                              hipStream_t stream) {
    (void)in_sizes; (void)n_in; (void)out_size; (void)ws_size;
    const float* s1   = (const float*)d_in[0];
    const float* s2   = (const float*)d_in[1];
    const float* mask = (const float*)d_in[2];
    const float* Wq   = (const float*)d_in[3];
    const float* bq   = (const float*)d_in[4];
    const float* Wk   = (const float*)d_in[5];
    const float* bk   = (const float*)d_in[6];
    const float* Wv   = (const float*)d_in[7];
    const float* bv   = (const float*)d_in[8];

    float* out_ctx  = (float*)d_out;
    float* out_attn = out_ctx + (size_t)B_ * N_ * HID;

    const size_t qkv = (size_t)B_ * NH * N_ * HD;   // 3,145,728 elems
    short* qbf  = (short*)d_ws;
    short* kbf  = qbf + qkv;
    short* vtb  = kbf + qkv;
    float* m_ws = (float*)(vtb + qkv);              // byte offset 6*qkv, 4B-aligned
    float* l_ws = m_ws + (size_t)B_ * NH * N_;

    dim3 g1((B_ * N_) / 64, HID / 64, 3);
    proj_kernel<<<g1, 256, 0, stream>>>(s1, s2, Wq, bq, Wk, bk, Wv, bv, qbf, kbf, vtb);

    dim3 g2(N_ / 64, NH, B_);
    flash_kernel<<<g2, 256, 0, stream>>>(qbf, kbf, vtb, mask, out_ctx, m_ws, l_ws);

    dim3 g3(N_ / 16, N_ / 256, B_);
    attnw_kernel<<<g3, 256, 0, stream>>>(qbf, kbf, mask, m_ws, l_ws, out_attn);
}

// Round 5
// 478.093 us; speedup vs baseline: 6.9300x; 1.2534x over previous
//
#include <hip/hip_runtime.h>
#include <stdint.h>

// Cross-attention forward: B=2, N1=N2=2048, HID=768, 12 heads x 64.
// Round 5: fix kw bug (768 is not pow2: & 767 != % 768); replace
// gload16+XOR-swizzle staging with reg-staged ds_write into row-padded LDS
// (stride 144 B) in both proj and flash. Double-buffered, loads issued
// before compute, ds_writes after (T14 shape).

typedef __attribute__((ext_vector_type(8))) short bf16x8;
typedef __attribute__((ext_vector_type(4))) short bf16x4;
typedef __attribute__((ext_vector_type(4))) float f32x4;

constexpr int B_  = 2;
constexpr int N_  = 2048;   // N1 == N2
constexpr int HID = 768;
constexpr int NH  = 12;
constexpr int HD  = 64;
constexpr int RS  = 144;    // LDS row stride bytes: 128 data + 16 pad

__device__ __forceinline__ short f2bf(float f) {   // RNE float->bf16
    uint32_t u = __builtin_bit_cast(uint32_t, f);
    u = (u + 0x7fffu + ((u >> 16) & 1u)) >> 16;
    return (short)u;
}

// ---------------------------------------------------------------------------
// P0a: X -> (hi|lo) bf16 rows of 1536.  hi = trunc-bf16(x), lo = RNE(x - hi).
// ---------------------------------------------------------------------------
__global__ __launch_bounds__(256) void prep_x(
    const float* __restrict__ s1, const float* __restrict__ s2,
    short* __restrict__ X1, short* __restrict__ X2)
{
    const int PT = (B_ * N_ * HID) / 4;
    int i = blockIdx.x * 256 + threadIdx.x;
    const float* S; short* X;
    if (i < PT) { S = s1; X = X1; } else { S = s2; X = X2; i -= PT; }
    const int e   = i * 4;
    const int row = e / HID;
    const int col = e - row * HID;
    const float4 v = *reinterpret_cast<const float4*>(&S[e]);
    float vs[4] = {v.x, v.y, v.z, v.w};
    short4 hi, lo;
    short* hp = &hi.x; short* lp = &lo.x;
    #pragma unroll
    for (int j = 0; j < 4; ++j) {
        const uint32_t u = __builtin_bit_cast(uint32_t, vs[j]);
        hp[j] = (short)(u >> 16);
        const float hif = __builtin_bit_cast(float, u & 0xffff0000u);
        lp[j] = f2bf(vs[j] - hif);
    }
    short* dst = X + (size_t)row * 1536 + col;
    *reinterpret_cast<short4*>(dst)       = hi;
    *reinterpret_cast<short4*>(dst + 768) = lo;
}

// ---------------------------------------------------------------------------
// P0b: W [k][n] fp32 -> WT [n][k] bf16 (3 matrices).  grid (12,12,3) x 256.
// ---------------------------------------------------------------------------
__global__ __launch_bounds__(256) void prep_w(
    const float* __restrict__ Wq, const float* __restrict__ Wk,
    const float* __restrict__ Wv, short* __restrict__ WT)
{
    const int z = blockIdx.z;
    const float* W = (z == 0) ? Wq : (z == 1) ? Wk : Wv;
    short* O = WT + (size_t)z * HID * HID;
    __shared__ short Tl[64][66];
    const int k0 = blockIdx.x * 64, n0 = blockIdx.y * 64;
    const int t = threadIdx.x;
    const int rr = t >> 4, cc = (t & 15) * 4;
    #pragma unroll
    for (int i = 0; i < 4; ++i) {
        const int row = i * 16 + rr;
        const float4 w = *reinterpret_cast<const float4*>(&W[(size_t)(k0 + row) * HID + n0 + cc]);
        Tl[cc + 0][row] = f2bf(w.x);
        Tl[cc + 1][row] = f2bf(w.y);
        Tl[cc + 2][row] = f2bf(w.z);
        Tl[cc + 3][row] = f2bf(w.w);
    }
    __syncthreads();
    #pragma unroll
    for (int i = 0; i < 4; ++i) {
        const int n = i * 16 + rr;
        short4 o;
        o.x = Tl[n][cc + 0]; o.y = Tl[n][cc + 1];
        o.z = Tl[n][cc + 2]; o.w = Tl[n][cc + 3];
        *reinterpret_cast<short4*>(&O[(size_t)(n0 + n) * HID + k0 + cc]) = o;
    }
}

// ---------------------------------------------------------------------------
// K1: proj GEMM (bf16 MFMA).  grid (32, 12, 3), block 256 (4 waves 2x2).
// Tile 128x64, BK=64. Reg-staged, double-buffered LDS (row stride RS=144).
// q,k: K'=1536 (hi then lo passes, W repeated); v: K'=768 (hi only).
// which=0: q*0.125 -> qb [bh][n][d]; 1: k -> kbm; 2: v -> vtb [bh][d][n].
// ---------------------------------------------------------------------------
__global__ __launch_bounds__(256) void proj_mfma(
    const short* __restrict__ X1, const short* __restrict__ X2,
    const short* __restrict__ WT,
    const float* __restrict__ bq, const float* __restrict__ bk,
    const float* __restrict__ bv,
    short* __restrict__ qb, short* __restrict__ kbm, short* __restrict__ vtb)
{
    const int which = blockIdx.z;
    const char* Xb = (const char*)((which == 0) ? X1 : X2);        // row 3072 B
    const char* Wb = (const char*)(WT + (size_t)which * HID * HID); // row 1536 B
    const float* bias = (which == 0) ? bq : (which == 1) ? bk : bv;
    const int m0 = blockIdx.x * 128;
    const int n0 = blockIdx.y * 64;
    const int t = threadIdx.x;
    const int lane = t & 63;
    const int lg = lane >> 4, lm = lane & 15;
    const int wave = t >> 6;
    const int wr = wave >> 1, wc = wave & 1;

    __shared__ __align__(16) char Al[2][128 * RS];   // 2 x 18432
    __shared__ __align__(16) char Bl[2][64 * RS];    // 2 x 9216

    const int KSTEPS = (which == 2) ? 12 : 24;

    f32x4 acc[4][2];
    #pragma unroll
    for (int mt = 0; mt < 4; ++mt)
        #pragma unroll
        for (int nt = 0; nt < 2; ++nt) acc[mt][nt] = f32x4{0.f, 0.f, 0.f, 0.f};

    int4 ra[4], rb[2];
    auto loadAB = [&](int ks) {
        const int ka = ks * 128;            // byte col into X row (hi then lo)
        const int kw = (ks % 12) * 128;     // byte col into WT row (W repeats)
        #pragma unroll
        for (int u = 0; u < 4; ++u) {
            const int c = u * 256 + t;      // chunk id: row=c>>3, j=c&7
            ra[u] = *reinterpret_cast<const int4*>(
                Xb + (size_t)(m0 + (c >> 3)) * 3072 + ka + (c & 7) * 16);
        }
        #pragma unroll
        for (int u = 0; u < 2; ++u) {
            const int c = u * 256 + t;
            rb[u] = *reinterpret_cast<const int4*>(
                Wb + (size_t)(n0 + (c >> 3)) * 1536 + kw + (c & 7) * 16);
        }
    };
    auto storeAB = [&](int buf) {
        #pragma unroll
        for (int u = 0; u < 4; ++u) {
            const int c = u * 256 + t;      // byte = row*RS + j*16 = c*16 + row*16
            *reinterpret_cast<int4*>(&Al[buf][c * 16 + (c >> 3) * 16]) = ra[u];
        }
        #pragma unroll
        for (int u = 0; u < 2; ++u) {
            const int c = u * 256 + t;
            *reinterpret_cast<int4*>(&Bl[buf][c * 16 + (c >> 3) * 16]) = rb[u];
        }
    };

    loadAB(0);
    storeAB(0);
    __syncthreads();

    for (int ks = 0; ks < KSTEPS; ++ks) {
        const bool more = (ks + 1 < KSTEPS);
        if (more) loadAB(ks + 1);           // VMEM in flight during compute
        const char* Ab = Al[ks & 1];
        const char* Bb = Bl[ks & 1];
        #pragma unroll
        for (int ksub = 0; ksub < 2; ++ksub) {
            const int jj = ksub * 4 + lg;
            bf16x8 a[4], bb[2];
            #pragma unroll
            for (int mt = 0; mt < 4; ++mt) {
                const int r = wr * 64 + mt * 16 + lm;
                a[mt] = *reinterpret_cast<const bf16x8*>(Ab + r * RS + jj * 16);
            }
            #pragma unroll
            for (int nt = 0; nt < 2; ++nt) {
                const int r = wc * 32 + nt * 16 + lm;
                bb[nt] = *reinterpret_cast<const bf16x8*>(Bb + r * RS + jj * 16);
            }
            #pragma unroll
            for (int mt = 0; mt < 4; ++mt)
                #pragma unroll
                for (int nt = 0; nt < 2; ++nt)
                    acc[mt][nt] = __builtin_amdgcn_mfma_f32_16x16x32_bf16(
                        a[mt], bb[nt], acc[mt][nt], 0, 0, 0);
        }
        if (more) storeAB((ks + 1) & 1);    // other buffer: no conflict w/ readers
        __syncthreads();
    }

    const int b = m0 >> 11;
    const int head = blockIdx.y;
    const size_t bh = (size_t)(b * NH + head);

    if (which != 2) {
        const float sc = (which == 0) ? 0.125f : 1.0f;   // fold 1/sqrt(64) into q
        short* dst = (which == 0) ? qb : kbm;
        #pragma unroll
        for (int mt = 0; mt < 4; ++mt)
            #pragma unroll
            for (int nt = 0; nt < 2; ++nt) {
                const int dd = wc * 32 + nt * 16 + lm;
                const float bi = bias[n0 + dd];
                #pragma unroll
                for (int r = 0; r < 4; ++r) {
                    const int m = m0 + wr * 64 + mt * 16 + 4 * lg + r;
                    const int n = m & 2047;
                    dst[(bh * N_ + n) * HD + dd] = f2bf((acc[mt][nt][r] + bi) * sc);
                }
            }
    } else {
        // transpose via LDS bounce for coalesced vtb stores
        short* Ct = (short*)Al[0];           // [64 d][128 m] bf16 = 16384 B
        #pragma unroll
        for (int mt = 0; mt < 4; ++mt)
            #pragma unroll
            for (int nt = 0; nt < 2; ++nt) {
                const int dd = wc * 32 + nt * 16 + lm;
                const float bi = bias[n0 + dd];
                #pragma unroll
                for (int r = 0; r < 4; ++r) {
                    const int ml = wr * 64 + mt * 16 + 4 * lg + r;
                    Ct[dd * 128 + ml] = f2bf(acc[mt][nt][r] + bi);
                }
            }
        __syncthreads();
        const int d = t >> 2, seg = t & 3;
        const short* src = Ct + d * 128 + seg * 32;
        short* dv = vtb + (bh * HD + d) * N_ + (m0 & 2047) + seg * 32;
        #pragma unroll
        for (int u = 0; u < 4; ++u)
            *reinterpret_cast<int4*>(dv + u * 8) = *reinterpret_cast<const int4*>(src + u * 8);
    }
}

// ---------------------------------------------------------------------------
// K2: flash attention.  grid (N/64, NH, B), block 256 (4 waves).
// K tile (64x64 bf16) reg-staged into padded LDS, double-buffered, shared by
// 4 waves. V/mask hoisted. S^T = mfma(K,Q); in-register online softmax;
// P (bf16-packed) feeds mfma_16x16x16bf16_1k PV directly.
// ---------------------------------------------------------------------------
__global__ __launch_bounds__(256) void flash_kernel(
    const short* __restrict__ qb, const short* __restrict__ kbm,
    const short* __restrict__ vtb, const float* __restrict__ mask,
    float* __restrict__ out_ctx, float* __restrict__ m_ws, float* __restrict__ l_ws)
{
    const int qt = blockIdx.x, h = blockIdx.y, b = blockIdx.z;
    const int t = threadIdx.x;
    const int lane = t & 63;
    const int wave = __builtin_amdgcn_readfirstlane(t >> 6);
    const int lg = lane >> 4, lm = lane & 15;
    const int q0 = qt * 64 + wave * 16;

    __shared__ __align__(16) char Kl[2][64 * RS];   // 2 x 9216

    const size_t bh = (size_t)(b * NH + h);
    const short* qp  = qb  + (bh * N_ + q0) * HD;
    const char*  kpb = (const char*)(kbm + bh * N_ * HD);   // row 128 B
    const short* vp  = vtb + bh * HD * N_;
    const float* mk  = mask + (size_t)b * N_;

    const bf16x8 qf0 = *reinterpret_cast<const bf16x8*>(qp + lm * HD + lg * 8);
    const bf16x8 qf1 = *reinterpret_cast<const bf16x8*>(qp + lm * HD + lg * 8 + 32);

    f32x4 cacc[4];
    #pragma unroll
    for (int vt = 0; vt < 4; ++vt) cacc[vt] = f32x4{0.f, 0.f, 0.f, 0.f};
    float m = -1e30f, l = 0.f;

    int4 rk[2];
    auto loadK = [&](int krow) {
        #pragma unroll
        for (int u = 0; u < 2; ++u) {
            const int c = u * 256 + t;
            rk[u] = *reinterpret_cast<const int4*>(
                kpb + (size_t)(krow + (c >> 3)) * 128 + (c & 7) * 16);
        }
    };
    auto storeK = [&](int buf) {
        #pragma unroll
        for (int u = 0; u < 2; ++u) {
            const int c = u * 256 + t;
            *reinterpret_cast<int4*>(&Kl[buf][c * 16 + (c >> 3) * 16]) = rk[u];
        }
    };

    loadK(0);
    storeK(0);
    __syncthreads();

    for (int k0 = 0; k0 < N_; k0 += 64) {
        const int cur  = (k0 >> 6) & 1;
        const bool more = (k0 + 64 < N_);

        // hoisted V + mask loads (consumed after softmax)
        bf16x4 vf[4][4];
        #pragma unroll
        for (int kt = 0; kt < 4; ++kt)
            #pragma unroll
            for (int vt = 0; vt < 4; ++vt)
                vf[kt][vt] = *reinterpret_cast<const bf16x4*>(
                    vp + (size_t)(vt * 16 + lm) * N_ + k0 + kt * 16 + lg * 4);
        f32x4 mv4[4];
        #pragma unroll
        for (int kt = 0; kt < 4; ++kt)
            mv4[kt] = *reinterpret_cast<const f32x4*>(&mk[k0 + kt * 16 + 4 * lg]);

        if (more) loadK(k0 + 64);           // VMEM in flight during compute

        // ---- S^T tiles from LDS K ----
        const char* Kb = Kl[cur];
        f32x4 accs[4];
        #pragma unroll
        for (int kt = 0; kt < 4; ++kt) {
            const int r = kt * 16 + lm;
            const bf16x8 kf0 = *reinterpret_cast<const bf16x8*>(Kb + r * RS + lg * 16);
            const bf16x8 kf1 = *reinterpret_cast<const bf16x8*>(Kb + r * RS + (lg + 4) * 16);
            f32x4 z = f32x4{0.f, 0.f, 0.f, 0.f};
            z = __builtin_amdgcn_mfma_f32_16x16x32_bf16(kf0, qf0, z, 0, 0, 0);
            z = __builtin_amdgcn_mfma_f32_16x16x32_bf16(kf1, qf1, z, 0, 0, 0);
            accs[kt] = z;
        }

        // ---- online softmax (per-lane q = lm) ----
        float p[4][4];
        float tmax = -3.0e38f;
        #pragma unroll
        for (int kt = 0; kt < 4; ++kt)
            #pragma unroll
            for (int r = 0; r < 4; ++r) {
                p[kt][r] = accs[kt][r] + mv4[kt][r];
                tmax = fmaxf(tmax, p[kt][r]);
            }
        tmax = fmaxf(tmax, __shfl_xor(tmax, 16));
        tmax = fmaxf(tmax, __shfl_xor(tmax, 32));
        const float mnew  = fmaxf(m, tmax);
        const float scale = __expf(m - mnew);
        float psum = 0.f;
        #pragma unroll
        for (int kt = 0; kt < 4; ++kt)
            #pragma unroll
            for (int r = 0; r < 4; ++r) { p[kt][r] = __expf(p[kt][r] - mnew); psum += p[kt][r]; }
        psum += __shfl_xor(psum, 16);
        psum += __shfl_xor(psum, 32);
        l = l * scale + psum;
        m = mnew;

        bf16x4 pa[4];
        #pragma unroll
        for (int kt = 0; kt < 4; ++kt) {
            bf16x4 tt;
            tt[0] = f2bf(p[kt][0]); tt[1] = f2bf(p[kt][1]);
            tt[2] = f2bf(p[kt][2]); tt[3] = f2bf(p[kt][3]);
            pa[kt] = tt;
        }
        #pragma unroll
        for (int r = 0; r < 4; ++r) {
            const float sr = __shfl(scale, lg * 4 + r);
            #pragma unroll
            for (int vt = 0; vt < 4; ++vt) cacc[vt][r] *= sr;
        }
        #pragma unroll
        for (int kt = 0; kt < 4; ++kt)
            #pragma unroll
            for (int vt = 0; vt < 4; ++vt)
                cacc[vt] = __builtin_amdgcn_mfma_f32_16x16x16bf16_1k(
                    pa[kt], vf[kt][vt], cacc[vt], 0, 0, 0);

        if (more) storeK(cur ^ 1);          // other buffer: safe before barrier
        __syncthreads();
    }

    const float invl = 1.f / l;
    #pragma unroll
    for (int r = 0; r < 4; ++r) {
        const float ir = __shfl(invl, lg * 4 + r);
        float* orow = out_ctx + ((size_t)b * N_ + q0 + lg * 4 + r) * HID + h * HD;
        #pragma unroll
        for (int vt = 0; vt < 4; ++vt) orow[vt * 16 + lm] = cacc[vt][r] * ir;
    }
    if (lane < 16) {
        m_ws[bh * N_ + q0 + lane] = m;
        l_ws[bh * N_ + q0 + lane] = l;
    }
}

// ---------------------------------------------------------------------------
// K3: attn_weights = sum_h probs / 12.  grid (N/16, N/256, B), block 256.
// ---------------------------------------------------------------------------
__global__ __launch_bounds__(256) void attnw_kernel(
    const short* __restrict__ qb, const short* __restrict__ kbm,
    const float* __restrict__ mask, const float* __restrict__ m_ws,
    const float* __restrict__ l_ws, float* __restrict__ out_attn)
{
    const int qt = blockIdx.x, ct = blockIdx.y, b = blockIdx.z;
    const int lane = threadIdx.x & 63;
    const int wave = threadIdx.x >> 6;
    const int lg = lane >> 4, lm = lane & 15;
    const int q0 = qt * 16;
    const int kbase = ct * 256 + wave * 64;

    float mv[4];
    #pragma unroll
    for (int kt = 0; kt < 4; ++kt) mv[kt] = mask[(size_t)b * N_ + kbase + kt * 16 + lm];

    f32x4 accw[4];
    #pragma unroll
    for (int kt = 0; kt < 4; ++kt) accw[kt] = f32x4{0.f, 0.f, 0.f, 0.f};

    for (int h = 0; h < NH; ++h) {
        const size_t bh = (size_t)(b * NH + h);
        const short* qp = qb + (bh * N_ + q0) * HD;
        const bf16x8 qf0 = *reinterpret_cast<const bf16x8*>(qp + lm * HD + lg * 8);
        const bf16x8 qf1 = *reinterpret_cast<const bf16x8*>(qp + lm * HD + lg * 8 + 32);
        const short* kp = kbm + bh * N_ * HD;
        float mr[4], il[4];
        #pragma unroll
        for (int r = 0; r < 4; ++r) {
            mr[r] = m_ws[bh * N_ + q0 + lg * 4 + r];
            il[r] = 1.f / l_ws[bh * N_ + q0 + lg * 4 + r];
        }
        #pragma unroll
        for (int kt = 0; kt < 4; ++kt) {
            const short* kr = kp + (size_t)(kbase + kt * 16 + lm) * HD + lg * 8;
            const bf16x8 kf0 = *reinterpret_cast<const bf16x8*>(kr);
            const bf16x8 kf1 = *reinterpret_cast<const bf16x8*>(kr + 32);
            f32x4 z = f32x4{0.f, 0.f, 0.f, 0.f};
            z = __builtin_amdgcn_mfma_f32_16x16x32_bf16(qf0, kf0, z, 0, 0, 0);
            z = __builtin_amdgcn_mfma_f32_16x16x32_bf16(qf1, kf1, z, 0, 0, 0);
            #pragma unroll
            for (int r = 0; r < 4; ++r)
                accw[kt][r] += __expf(z[r] + mv[kt] - mr[r]) * il[r];
        }
    }
    #pragma unroll
    for (int kt = 0; kt < 4; ++kt)
        #pragma unroll
        for (int r = 0; r < 4; ++r)
            out_attn[((size_t)b * N_ + q0 + lg * 4 + r) * N_ + kbase + kt * 16 + lm]
                = accw[kt][r] * (1.0f / 12.0f);
}

// ---------------------------------------------------------------------------
extern "C" void kernel_launch(void* const* d_in, const int* in_sizes, int n_in,
                              void* d_out, int out_size, void* d_ws, size_t ws_size,
                              hipStream_t stream) {
    (void)in_sizes; (void)n_in; (void)out_size;
    const float* s1   = (const float*)d_in[0];
    const float* s2   = (const float*)d_in[1];
    const float* mask = (const float*)d_in[2];
    const float* Wq   = (const float*)d_in[3];
    const float* bq   = (const float*)d_in[4];
    const float* Wk   = (const float*)d_in[5];
    const float* bk   = (const float*)d_in[6];
    const float* Wv   = (const float*)d_in[7];
    const float* bv   = (const float*)d_in[8];

    float* out_ctx  = (float*)d_out;
    float* out_attn = out_ctx + (size_t)B_ * N_ * HID;

    const size_t xlen = (size_t)B_ * N_ * 1536;     // hi|lo shorts per tensor
    const size_t qkv  = (size_t)B_ * NH * N_ * HD;
    short* X1  = (short*)d_ws;
    short* X2  = X1 + xlen;
    short* WT  = X2 + xlen;
    short* qb  = WT + (size_t)3 * HID * HID;
    short* kbm = qb + qkv;
    short* vtb = kbm + qkv;
    float* m_ws = (float*)(vtb + qkv);
    float* l_ws = m_ws + (size_t)B_ * NH * N_;
    const size_t need = (size_t)((char*)(l_ws + (size_t)B_ * NH * N_) - (char*)d_ws);
    if (ws_size < need) return;

    prep_x<<<6144, 256, 0, stream>>>(s1, s2, X1, X2);
    prep_w<<<dim3(12, 12, 3), 256, 0, stream>>>(Wq, Wk, Wv, WT);
    proj_mfma<<<dim3(32, 12, 3), 256, 0, stream>>>(X1, X2, WT, bq, bk, bv, qb, kbm, vtb);
    flash_kernel<<<dim3(N_ / 64, NH, B_), 256, 0, stream>>>(qb, kbm, vtb, mask,
                                                            out_ctx, m_ws, l_ws);
    attnw_kernel<<<dim3(N_ / 16, N_ / 256, B_), 256, 0, stream>>>(qb, kbm, mask,
                                                                  m_ws, l_ws, out_attn);
}

// Round 6
// 475.075 us; speedup vs baseline: 6.9740x; 1.0064x over previous
//
#include <hip/hip_runtime.h>
#include <stdint.h>

// Cross-attention forward: B=2, N1=N2=2048, HID=768, 12 heads x 64.
// Round 6: split-K flash (2-way flash-decoding) to lift the grid-capped
// 37.5% occupancy to 75%; exact online-softmax merge kernel; setprio
// around MFMA clusters. proj/attnw/prep unchanged from round 5 (passing).

typedef __attribute__((ext_vector_type(8))) short bf16x8;
typedef __attribute__((ext_vector_type(4))) short bf16x4;
typedef __attribute__((ext_vector_type(4))) float f32x4;

constexpr int B_  = 2;
constexpr int N_  = 2048;   // N1 == N2
constexpr int HID = 768;
constexpr int NH  = 12;
constexpr int HD  = 64;
constexpr int RS  = 144;    // LDS row stride bytes: 128 data + 16 pad
constexpr int NSPLIT = 2;   // key-range splits in flash
constexpr int KSPAN  = N_ / NSPLIT;   // 1024 keys per split

__device__ __forceinline__ short f2bf(float f) {   // RNE float->bf16
    uint32_t u = __builtin_bit_cast(uint32_t, f);
    u = (u + 0x7fffu + ((u >> 16) & 1u)) >> 16;
    return (short)u;
}

// ---------------------------------------------------------------------------
// P0a: X -> (hi|lo) bf16 rows of 1536.  hi = trunc-bf16(x), lo = RNE(x - hi).
// ---------------------------------------------------------------------------
__global__ __launch_bounds__(256) void prep_x(
    const float* __restrict__ s1, const float* __restrict__ s2,
    short* __restrict__ X1, short* __restrict__ X2)
{
    const int PT = (B_ * N_ * HID) / 4;
    int i = blockIdx.x * 256 + threadIdx.x;
    const float* S; short* X;
    if (i < PT) { S = s1; X = X1; } else { S = s2; X = X2; i -= PT; }
    const int e   = i * 4;
    const int row = e / HID;
    const int col = e - row * HID;
    const float4 v = *reinterpret_cast<const float4*>(&S[e]);
    float vs[4] = {v.x, v.y, v.z, v.w};
    short4 hi, lo;
    short* hp = &hi.x; short* lp = &lo.x;
    #pragma unroll
    for (int j = 0; j < 4; ++j) {
        const uint32_t u = __builtin_bit_cast(uint32_t, vs[j]);
        hp[j] = (short)(u >> 16);
        const float hif = __builtin_bit_cast(float, u & 0xffff0000u);
        lp[j] = f2bf(vs[j] - hif);
    }
    short* dst = X + (size_t)row * 1536 + col;
    *reinterpret_cast<short4*>(dst)       = hi;
    *reinterpret_cast<short4*>(dst + 768) = lo;
}

// ---------------------------------------------------------------------------
// P0b: W [k][n] fp32 -> WT [n][k] bf16 (3 matrices).  grid (12,12,3) x 256.
// ---------------------------------------------------------------------------
__global__ __launch_bounds__(256) void prep_w(
    const float* __restrict__ Wq, const float* __restrict__ Wk,
    const float* __restrict__ Wv, short* __restrict__ WT)
{
    const int z = blockIdx.z;
    const float* W = (z == 0) ? Wq : (z == 1) ? Wk : Wv;
    short* O = WT + (size_t)z * HID * HID;
    __shared__ short Tl[64][66];
    const int k0 = blockIdx.x * 64, n0 = blockIdx.y * 64;
    const int t = threadIdx.x;
    const int rr = t >> 4, cc = (t & 15) * 4;
    #pragma unroll
    for (int i = 0; i < 4; ++i) {
        const int row = i * 16 + rr;
        const float4 w = *reinterpret_cast<const float4*>(&W[(size_t)(k0 + row) * HID + n0 + cc]);
        Tl[cc + 0][row] = f2bf(w.x);
        Tl[cc + 1][row] = f2bf(w.y);
        Tl[cc + 2][row] = f2bf(w.z);
        Tl[cc + 3][row] = f2bf(w.w);
    }
    __syncthreads();
    #pragma unroll
    for (int i = 0; i < 4; ++i) {
        const int n = i * 16 + rr;
        short4 o;
        o.x = Tl[n][cc + 0]; o.y = Tl[n][cc + 1];
        o.z = Tl[n][cc + 2]; o.w = Tl[n][cc + 3];
        *reinterpret_cast<short4*>(&O[(size_t)(n0 + n) * HID + k0 + cc]) = o;
    }
}

// ---------------------------------------------------------------------------
// K1: proj GEMM (bf16 MFMA).  grid (32, 12, 3), block 256 (4 waves 2x2).
// Tile 128x64, BK=64. Reg-staged, double-buffered LDS (row stride RS=144).
// q,k: K'=1536 (hi then lo passes, W repeated); v: K'=768 (hi only).
// which=0: q*0.125 -> qb [bh][n][d]; 1: k -> kbm; 2: v -> vtb [bh][d][n].
// ---------------------------------------------------------------------------
__global__ __launch_bounds__(256) void proj_mfma(
    const short* __restrict__ X1, const short* __restrict__ X2,
    const short* __restrict__ WT,
    const float* __restrict__ bq, const float* __restrict__ bk,
    const float* __restrict__ bv,
    short* __restrict__ qb, short* __restrict__ kbm, short* __restrict__ vtb)
{
    const int which = blockIdx.z;
    const char* Xb = (const char*)((which == 0) ? X1 : X2);        // row 3072 B
    const char* Wb = (const char*)(WT + (size_t)which * HID * HID); // row 1536 B
    const float* bias = (which == 0) ? bq : (which == 1) ? bk : bv;
    const int m0 = blockIdx.x * 128;
    const int n0 = blockIdx.y * 64;
    const int t = threadIdx.x;
    const int lane = t & 63;
    const int lg = lane >> 4, lm = lane & 15;
    const int wave = t >> 6;
    const int wr = wave >> 1, wc = wave & 1;

    __shared__ __align__(16) char Al[2][128 * RS];   // 2 x 18432
    __shared__ __align__(16) char Bl[2][64 * RS];    // 2 x 9216

    const int KSTEPS = (which == 2) ? 12 : 24;

    f32x4 acc[4][2];
    #pragma unroll
    for (int mt = 0; mt < 4; ++mt)
        #pragma unroll
        for (int nt = 0; nt < 2; ++nt) acc[mt][nt] = f32x4{0.f, 0.f, 0.f, 0.f};

    int4 ra[4], rb[2];
    auto loadAB = [&](int ks) {
        const int ka = ks * 128;            // byte col into X row (hi then lo)
        const int kw = (ks % 12) * 128;     // byte col into WT row (W repeats)
        #pragma unroll
        for (int u = 0; u < 4; ++u) {
            const int c = u * 256 + t;      // chunk id: row=c>>3, j=c&7
            ra[u] = *reinterpret_cast<const int4*>(
                Xb + (size_t)(m0 + (c >> 3)) * 3072 + ka + (c & 7) * 16);
        }
        #pragma unroll
        for (int u = 0; u < 2; ++u) {
            const int c = u * 256 + t;
            rb[u] = *reinterpret_cast<const int4*>(
                Wb + (size_t)(n0 + (c >> 3)) * 1536 + kw + (c & 7) * 16);
        }
    };
    auto storeAB = [&](int buf) {
        #pragma unroll
        for (int u = 0; u < 4; ++u) {
            const int c = u * 256 + t;      // byte = row*RS + j*16 = c*16 + row*16
            *reinterpret_cast<int4*>(&Al[buf][c * 16 + (c >> 3) * 16]) = ra[u];
        }
        #pragma unroll
        for (int u = 0; u < 2; ++u) {
            const int c = u * 256 + t;
            *reinterpret_cast<int4*>(&Bl[buf][c * 16 + (c >> 3) * 16]) = rb[u];
        }
    };

    loadAB(0);
    storeAB(0);
    __syncthreads();

    for (int ks = 0; ks < KSTEPS; ++ks) {
        const bool more = (ks + 1 < KSTEPS);
        if (more) loadAB(ks + 1);           // VMEM in flight during compute
        const char* Ab = Al[ks & 1];
        const char* Bb = Bl[ks & 1];
        #pragma unroll
        for (int ksub = 0; ksub < 2; ++ksub) {
            const int jj = ksub * 4 + lg;
            bf16x8 a[4], bb[2];
            #pragma unroll
            for (int mt = 0; mt < 4; ++mt) {
                const int r = wr * 64 + mt * 16 + lm;
                a[mt] = *reinterpret_cast<const bf16x8*>(Ab + r * RS + jj * 16);
            }
            #pragma unroll
            for (int nt = 0; nt < 2; ++nt) {
                const int r = wc * 32 + nt * 16 + lm;
                bb[nt] = *reinterpret_cast<const bf16x8*>(Bb + r * RS + jj * 16);
            }
            __builtin_amdgcn_s_setprio(1);
            #pragma unroll
            for (int mt = 0; mt < 4; ++mt)
                #pragma unroll
                for (int nt = 0; nt < 2; ++nt)
                    acc[mt][nt] = __builtin_amdgcn_mfma_f32_16x16x32_bf16(
                        a[mt], bb[nt], acc[mt][nt], 0, 0, 0);
            __builtin_amdgcn_s_setprio(0);
        }
        if (more) storeAB((ks + 1) & 1);    // other buffer: no conflict w/ readers
        __syncthreads();
    }

    const int b = m0 >> 11;
    const int head = blockIdx.y;
    const size_t bh = (size_t)(b * NH + head);

    if (which != 2) {
        const float sc = (which == 0) ? 0.125f : 1.0f;   // fold 1/sqrt(64) into q
        short* dst = (which == 0) ? qb : kbm;
        #pragma unroll
        for (int mt = 0; mt < 4; ++mt)
            #pragma unroll
            for (int nt = 0; nt < 2; ++nt) {
                const int dd = wc * 32 + nt * 16 + lm;
                const float bi = bias[n0 + dd];
                #pragma unroll
                for (int r = 0; r < 4; ++r) {
                    const int m = m0 + wr * 64 + mt * 16 + 4 * lg + r;
                    const int n = m & 2047;
                    dst[(bh * N_ + n) * HD + dd] = f2bf((acc[mt][nt][r] + bi) * sc);
                }
            }
    } else {
        // transpose via LDS bounce for coalesced vtb stores
        short* Ct = (short*)Al[0];           // [64 d][128 m] bf16 = 16384 B
        #pragma unroll
        for (int mt = 0; mt < 4; ++mt)
            #pragma unroll
            for (int nt = 0; nt < 2; ++nt) {
                const int dd = wc * 32 + nt * 16 + lm;
                const float bi = bias[n0 + dd];
                #pragma unroll
                for (int r = 0; r < 4; ++r) {
                    const int ml = wr * 64 + mt * 16 + 4 * lg + r;
                    Ct[dd * 128 + ml] = f2bf(acc[mt][nt][r] + bi);
                }
            }
        __syncthreads();
        const int d = t >> 2, seg = t & 3;
        const short* src = Ct + d * 128 + seg * 32;
        short* dv = vtb + (bh * HD + d) * N_ + (m0 & 2047) + seg * 32;
        #pragma unroll
        for (int u = 0; u < 4; ++u)
            *reinterpret_cast<int4*>(dv + u * 8) = *reinterpret_cast<const int4*>(src + u * 8);
    }
}

// ---------------------------------------------------------------------------
// K2: split-K flash.  grid (N/64, NH, B*NSPLIT), block 256 (4 waves).
// z = b*NSPLIT + s; block handles keys [s*KSPAN, (s+1)*KSPAN).
// Writes UNNORMALIZED partial ctx (s=0 -> out_ctx region, s=1 -> ctx1, both
// in final [b][n][HID] layout) + per-row (m,l) partials.  K tile in LDS
// (reg-staged, padded, double-buffered); V scattered from L2 (it fits).
// ---------------------------------------------------------------------------
__global__ __launch_bounds__(256) void flash_kernel(
    const short* __restrict__ qb, const short* __restrict__ kbm,
    const short* __restrict__ vtb, const float* __restrict__ mask,
    float* __restrict__ ctx0, float* __restrict__ ctx1,
    float* __restrict__ m_part, float* __restrict__ l_part)
{
    const int qt = blockIdx.x, h = blockIdx.y;
    const int b = blockIdx.z / NSPLIT, s = blockIdx.z % NSPLIT;
    const int t = threadIdx.x;
    const int lane = t & 63;
    const int wave = __builtin_amdgcn_readfirstlane(t >> 6);
    const int lg = lane >> 4, lm = lane & 15;
    const int q0 = qt * 64 + wave * 16;
    const int kstart = s * KSPAN, kend = kstart + KSPAN;

    __shared__ __align__(16) char Kl[2][64 * RS];   // 2 x 9216

    const size_t bh = (size_t)(b * NH + h);
    const short* qp  = qb  + (bh * N_ + q0) * HD;
    const char*  kpb = (const char*)(kbm + bh * N_ * HD);   // row 128 B
    const short* vp  = vtb + bh * HD * N_;
    const float* mk  = mask + (size_t)b * N_;

    const bf16x8 qf0 = *reinterpret_cast<const bf16x8*>(qp + lm * HD + lg * 8);
    const bf16x8 qf1 = *reinterpret_cast<const bf16x8*>(qp + lm * HD + lg * 8 + 32);

    f32x4 cacc[4];
    #pragma unroll
    for (int vt = 0; vt < 4; ++vt) cacc[vt] = f32x4{0.f, 0.f, 0.f, 0.f};
    float m = -1e30f, l = 0.f;

    int4 rk[2];
    auto loadK = [&](int krow) {
        #pragma unroll
        for (int u = 0; u < 2; ++u) {
            const int c = u * 256 + t;
            rk[u] = *reinterpret_cast<const int4*>(
                kpb + (size_t)(krow + (c >> 3)) * 128 + (c & 7) * 16);
        }
    };
    auto storeK = [&](int buf) {
        #pragma unroll
        for (int u = 0; u < 2; ++u) {
            const int c = u * 256 + t;
            *reinterpret_cast<int4*>(&Kl[buf][c * 16 + (c >> 3) * 16]) = rk[u];
        }
    };

    loadK(kstart);
    storeK(0);
    __syncthreads();

    for (int k0 = kstart; k0 < kend; k0 += 64) {
        const int cur  = ((k0 - kstart) >> 6) & 1;
        const bool more = (k0 + 64 < kend);

        // hoisted V + mask loads (consumed after softmax)
        bf16x4 vf[4][4];
        #pragma unroll
        for (int kt = 0; kt < 4; ++kt)
            #pragma unroll
            for (int vt = 0; vt < 4; ++vt)
                vf[kt][vt] = *reinterpret_cast<const bf16x4*>(
                    vp + (size_t)(vt * 16 + lm) * N_ + k0 + kt * 16 + lg * 4);
        f32x4 mv4[4];
        #pragma unroll
        for (int kt = 0; kt < 4; ++kt)
            mv4[kt] = *reinterpret_cast<const f32x4*>(&mk[k0 + kt * 16 + 4 * lg]);

        if (more) loadK(k0 + 64);           // VMEM in flight during compute

        // ---- S^T tiles from LDS K ----
        const char* Kb = Kl[cur];
        f32x4 accs[4];
        __builtin_amdgcn_s_setprio(1);
        #pragma unroll
        for (int kt = 0; kt < 4; ++kt) {
            const int r = kt * 16 + lm;
            const bf16x8 kf0 = *reinterpret_cast<const bf16x8*>(Kb + r * RS + lg * 16);
            const bf16x8 kf1 = *reinterpret_cast<const bf16x8*>(Kb + r * RS + (lg + 4) * 16);
            f32x4 z = f32x4{0.f, 0.f, 0.f, 0.f};
            z = __builtin_amdgcn_mfma_f32_16x16x32_bf16(kf0, qf0, z, 0, 0, 0);
            z = __builtin_amdgcn_mfma_f32_16x16x32_bf16(kf1, qf1, z, 0, 0, 0);
            accs[kt] = z;
        }
        __builtin_amdgcn_s_setprio(0);

        // ---- online softmax (per-lane q = lm) ----
        float p[4][4];
        float tmax = -3.0e38f;
        #pragma unroll
        for (int kt = 0; kt < 4; ++kt)
            #pragma unroll
            for (int r = 0; r < 4; ++r) {
                p[kt][r] = accs[kt][r] + mv4[kt][r];
                tmax = fmaxf(tmax, p[kt][r]);
            }
        tmax = fmaxf(tmax, __shfl_xor(tmax, 16));
        tmax = fmaxf(tmax, __shfl_xor(tmax, 32));
        const float mnew  = fmaxf(m, tmax);
        const float scale = __expf(m - mnew);
        float psum = 0.f;
        #pragma unroll
        for (int kt = 0; kt < 4; ++kt)
            #pragma unroll
            for (int r = 0; r < 4; ++r) { p[kt][r] = __expf(p[kt][r] - mnew); psum += p[kt][r]; }
        psum += __shfl_xor(psum, 16);
        psum += __shfl_xor(psum, 32);
        l = l * scale + psum;
        m = mnew;

        bf16x4 pa[4];
        #pragma unroll
        for (int kt = 0; kt < 4; ++kt) {
            bf16x4 tt;
            tt[0] = f2bf(p[kt][0]); tt[1] = f2bf(p[kt][1]);
            tt[2] = f2bf(p[kt][2]); tt[3] = f2bf(p[kt][3]);
            pa[kt] = tt;
        }
        #pragma unroll
        for (int r = 0; r < 4; ++r) {
            const float sr = __shfl(scale, lg * 4 + r);
            #pragma unroll
            for (int vt = 0; vt < 4; ++vt) cacc[vt][r] *= sr;
        }
        __builtin_amdgcn_s_setprio(1);
        #pragma unroll
        for (int kt = 0; kt < 4; ++kt)
            #pragma unroll
            for (int vt = 0; vt < 4; ++vt)
                cacc[vt] = __builtin_amdgcn_mfma_f32_16x16x16bf16_1k(
                    pa[kt], vf[kt][vt], cacc[vt], 0, 0, 0);
        __builtin_amdgcn_s_setprio(0);

        if (more) storeK(cur ^ 1);          // other buffer: safe before barrier
        __syncthreads();
    }

    // unnormalized partial write (final [b][n][HID] layout)
    float* ctxp = (s == 0) ? ctx0 : ctx1;
    #pragma unroll
    for (int r = 0; r < 4; ++r) {
        float* orow = ctxp + ((size_t)b * N_ + q0 + lg * 4 + r) * HID + h * HD;
        #pragma unroll
        for (int vt = 0; vt < 4; ++vt) orow[vt * 16 + lm] = cacc[vt][r];
    }
    if (lane < 16) {
        const size_t idx = (size_t)s * (B_ * NH * N_) + bh * N_ + q0 + lane;
        m_part[idx] = m;
        l_part[idx] = l;
    }
}

// ---------------------------------------------------------------------------
// K2b: merge the NSPLIT=2 partials.  One wave per (bh,n) row; lane = d.
// out = (w0*c0 + w1*c1) / (w0*l0 + w1*l1),  w_s = exp(m_s - max(m0,m1)).
// Also writes final m_ws, l_ws for attnw.  grid 12288 x 256.
// ---------------------------------------------------------------------------
__global__ __launch_bounds__(256) void merge_kernel(
    float* __restrict__ ctx0, const float* __restrict__ ctx1,
    const float* __restrict__ m_part, const float* __restrict__ l_part,
    float* __restrict__ m_ws, float* __restrict__ l_ws)
{
    const int gid  = blockIdx.x * 256 + threadIdx.x;
    const int row  = gid >> 6;           // bh*N + n, 0..49151
    const int lane = gid & 63;           // d
    const int bh = row >> 11;            // row / N_
    const int n  = row & 2047;
    const int b  = bh / NH, h = bh % NH;
    constexpr int PS = B_ * NH * N_;

    const float m0 = m_part[row], m1 = m_part[PS + row];
    const float l0 = l_part[row], l1 = l_part[PS + row];
    const float M  = fmaxf(m0, m1);
    const float w0 = __expf(m0 - M), w1 = __expf(m1 - M);
    const float L  = w0 * l0 + w1 * l1;
    const float invL = 1.f / L;

    const size_t cidx = ((size_t)b * N_ + n) * HID + h * HD + lane;
    ctx0[cidx] = (w0 * ctx0[cidx] + w1 * ctx1[cidx]) * invL;

    if (lane == 0) { m_ws[row] = M; l_ws[row] = L; }
}

// ---------------------------------------------------------------------------
// K3: attn_weights = sum_h probs / 12.  grid (N/16, N/256, B), block 256.
// ---------------------------------------------------------------------------
__global__ __launch_bounds__(256) void attnw_kernel(
    const short* __restrict__ qb, const short* __restrict__ kbm,
    const float* __restrict__ mask, const float* __restrict__ m_ws,
    const float* __restrict__ l_ws, float* __restrict__ out_attn)
{
    const int qt = blockIdx.x, ct = blockIdx.y, b = blockIdx.z;
    const int lane = threadIdx.x & 63;
    const int wave = threadIdx.x >> 6;
    const int lg = lane >> 4, lm = lane & 15;
    const int q0 = qt * 16;
    const int kbase = ct * 256 + wave * 64;

    float mv[4];
    #pragma unroll
    for (int kt = 0; kt < 4; ++kt) mv[kt] = mask[(size_t)b * N_ + kbase + kt * 16 + lm];

    f32x4 accw[4];
    #pragma unroll
    for (int kt = 0; kt < 4; ++kt) accw[kt] = f32x4{0.f, 0.f, 0.f, 0.f};

    for (int h = 0; h < NH; ++h) {
        const size_t bh = (size_t)(b * NH + h);
        const short* qp = qb + (bh * N_ + q0) * HD;
        const bf16x8 qf0 = *reinterpret_cast<const bf16x8*>(qp + lm * HD + lg * 8);
        const bf16x8 qf1 = *reinterpret_cast<const bf16x8*>(qp + lm * HD + lg * 8 + 32);
        const short* kp = kbm + bh * N_ * HD;
        float mr[4], il[4];
        #pragma unroll
        for (int r = 0; r < 4; ++r) {
            mr[r] = m_ws[bh * N_ + q0 + lg * 4 + r];
            il[r] = 1.f / l_ws[bh * N_ + q0 + lg * 4 + r];
        }
        #pragma unroll
        for (int kt = 0; kt < 4; ++kt) {
            const short* kr = kp + (size_t)(kbase + kt * 16 + lm) * HD + lg * 8;
            const bf16x8 kf0 = *reinterpret_cast<const bf16x8*>(kr);
            const bf16x8 kf1 = *reinterpret_cast<const bf16x8*>(kr + 32);
            f32x4 z = f32x4{0.f, 0.f, 0.f, 0.f};
            z = __builtin_amdgcn_mfma_f32_16x16x32_bf16(qf0, kf0, z, 0, 0, 0);
            z = __builtin_amdgcn_mfma_f32_16x16x32_bf16(qf1, kf1, z, 0, 0, 0);
            #pragma unroll
            for (int r = 0; r < 4; ++r)
                accw[kt][r] += __expf(z[r] + mv[kt] - mr[r]) * il[r];
        }
    }
    #pragma unroll
    for (int kt = 0; kt < 4; ++kt)
        #pragma unroll
        for (int r = 0; r < 4; ++r)
            out_attn[((size_t)b * N_ + q0 + lg * 4 + r) * N_ + kbase + kt * 16 + lm]
                = accw[kt][r] * (1.0f / 12.0f);
}

// ---------------------------------------------------------------------------
extern "C" void kernel_launch(void* const* d_in, const int* in_sizes, int n_in,
                              void* d_out, int out_size, void* d_ws, size_t ws_size,
                              hipStream_t stream) {
    (void)in_sizes; (void)n_in; (void)out_size;
    const float* s1   = (const float*)d_in[0];
    const float* s2   = (const float*)d_in[1];
    const float* mask = (const float*)d_in[2];
    const float* Wq   = (const float*)d_in[3];
    const float* bq   = (const float*)d_in[4];
    const float* Wk   = (const float*)d_in[5];
    const float* bk   = (const float*)d_in[6];
    const float* Wv   = (const float*)d_in[7];
    const float* bv   = (const float*)d_in[8];

    float* out_ctx  = (float*)d_out;
    float* out_attn = out_ctx + (size_t)B_ * N_ * HID;

    const size_t xlen = (size_t)B_ * N_ * 1536;     // hi|lo shorts per tensor
    const size_t qkv  = (size_t)B_ * NH * N_ * HD;
    const size_t rows = (size_t)B_ * NH * N_;       // 49152
    short* X1   = (short*)d_ws;
    short* X2   = X1 + xlen;
    short* WT   = X2 + xlen;
    short* qb   = WT + (size_t)3 * HID * HID;
    short* kbm  = qb + qkv;
    short* vtb  = kbm + qkv;
    float* ctx1 = (float*)(vtb + qkv);               // [B][N][HID] partial s=1
    float* m_part = ctx1 + (size_t)B_ * N_ * HID;    // [NSPLIT][rows]
    float* l_part = m_part + NSPLIT * rows;
    float* m_ws   = l_part + NSPLIT * rows;
    float* l_ws   = m_ws + rows;
    const size_t need = (size_t)((char*)(l_ws + rows) - (char*)d_ws);
    if (ws_size < need) return;

    prep_x<<<6144, 256, 0, stream>>>(s1, s2, X1, X2);
    prep_w<<<dim3(12, 12, 3), 256, 0, stream>>>(Wq, Wk, Wv, WT);
    proj_mfma<<<dim3(32, 12, 3), 256, 0, stream>>>(X1, X2, WT, bq, bk, bv, qb, kbm, vtb);
    flash_kernel<<<dim3(N_ / 64, NH, B_ * NSPLIT), 256, 0, stream>>>(
        qb, kbm, vtb, mask, out_ctx, ctx1, m_part, l_part);
    merge_kernel<<<(B_ * N_ * HID) / 256, 256, 0, stream>>>(
        out_ctx, ctx1, m_part, l_part, m_ws, l_ws);
    attnw_kernel<<<dim3(N_ / 16, N_ / 256, B_), 256, 0, stream>>>(
        qb, kbm, mask, m_ws, l_ws, out_attn);
}